// Round 14
// baseline (441.734 us; speedup 1.0000x reference)
//
#include <hip/hip_runtime.h>
#include <math.h>

#define C_DIM 4
#define T_DIM 4096
#define D_DIM 1024
#define E_DIM 16
#define CAP   320
#define CT    (C_DIM * T_DIM)               // 16384 tokens
#define OUT_ONE ((size_t)CT * E_DIM * CAP)  // 83,886,080 elements per big output

#define NBLOCKS 1024                         // 16 tokens per block (4 per wave)
#define N4      ((2 * OUT_ONE) / 4)          // 41,943,040 float4 to zero
#define F4_PER_BLOCK (N4 / NBLOCKS)          // 40960 float4 per block (640KB)

// compile-time 6-bit bit-reverse (flatten permutation for the butterfly reduce)
__host__ __device__ constexpr int bitrev6(int i) {
    return ((i & 1) << 5) | ((i & 2) << 3) | ((i & 4) << 1)
         | ((i & 8) >> 1) | ((i & 16) >> 3) | ((i & 32) >> 5);
}

// ws layout (bytes):
//   0      : auxpart f32[64]   (per-(c,e) softmax prob sums) - zeroed each call
//   256    : counts  i32[64]   (per-(c,e) argmax histogram)  - zeroed each call
//   512    : gate    f32[CT]
//   66048  : index   i32[CT]

// async global->LDS, 16B per lane: LDS dest = uniform base + lane*16,
// global src = per-lane address (must include lane offset).
__device__ __forceinline__ void gl_lds16(const float* g, float* l) {
    __builtin_amdgcn_global_load_lds(
        (const __attribute__((address_space(1))) void*)g,
        (__attribute__((address_space(3))) void*)l,
        16, 0, 0);
}

// stage one 256-float chunk (r) of 4 tokens' in+noise into this wave's LDS buf:
// 8 fire-and-forget instructions, 1KB each, no VGPR destinations.
__device__ __forceinline__ void stage_chunk(
    const float* __restrict__ in, const float* __restrict__ noise,
    float (*buf)[256], int g0, int r, int lane)
{
    const size_t base = (size_t)g0 * D_DIM + r * 256 + lane * 4;
    #pragma unroll
    for (int j = 0; j < 4; ++j)
        gl_lds16(in + base + (size_t)j * D_DIM, &buf[j][0]);
    #pragma unroll
    for (int j = 0; j < 4; ++j)
        gl_lds16(noise + base + (size_t)j * D_DIM, &buf[4 + j][0]);
}

// consume one staged chunk: x = in*noise from LDS (ds_read_b128, conflict-free
// lane*16B), FMA against 16 W rows (L1/L2-cached global float4 loads).
__device__ __forceinline__ void compute_chunk(
    const float* __restrict__ w, float (*buf)[256], float* val, int r, int lane)
{
    const int d0 = r * 256 + lane * 4;
    float4 x[4];
    #pragma unroll
    for (int tk = 0; tk < 4; ++tk) {
        const float4 a = *(const float4*)&buf[tk][lane * 4];
        const float4 n = *(const float4*)&buf[4 + tk][lane * 4];
        x[tk] = make_float4(a.x * n.x, a.y * n.y, a.z * n.z, a.w * n.w);
    }
    #pragma unroll
    for (int e = 0; e < 16; ++e) {
        const float4 wv4 = *(const float4*)(w + e * D_DIM + d0);
        #pragma unroll
        for (int tk = 0; tk < 4; ++tk)
            val[bitrev6(tk * 16 + e)] += x[tk].x * wv4.x + x[tk].y * wv4.y
                                       + x[tk].z * wv4.z + x[tk].w * wv4.w;
    }
}

// ---------------------------------------------------------------------------
// R8 structure (best: 171us) + async global_load_lds staging of in/noise.
// The router read phase was latency-bound: ~8-16 VGPR-destination loads in
// flight/wave ~= 2 TB/s. global_load_lds has no VGPR dest -> 16 x 1KB in
// flight per wave (2-chunk pipeline, counted vmcnt(8)), read phase at BW.
// Staging is wave-private (each wave stages its own 4 tokens) -> no barriers.
// ---------------------------------------------------------------------------
__global__ void fused_router_fill_kernel(
    const float* __restrict__ in, const float* __restrict__ w,
    const float* __restrict__ noise, float* __restrict__ gate,
    int* __restrict__ index, float* __restrict__ auxpart,
    int* __restrict__ counts, float4* __restrict__ out4)
{
    __shared__ float stage_lds[4][2][8][256];   // wave, dbuf, {4 in,4 noise}, 64KB
    __shared__ float psum[E_DIM];
    __shared__ int   hcnt[E_DIM];
    const int tid = threadIdx.x;
    if (tid < E_DIM) { psum[tid] = 0.0f; hcnt[tid] = 0; }
    __syncthreads();

    const int wave = tid >> 6;
    const int lane = tid & 63;
    const int g0   = blockIdx.x * 16 + wave * 4;   // 4 tokens per wave

    const float4 z = make_float4(0.f, 0.f, 0.f, 0.f);
    float4* dst = out4 + (size_t)blockIdx.x * F4_PER_BLOCK;

    // ---- odd blocks: fill first (stagger parity, R7/R8-proven) ----
    if (blockIdx.x & 1) {
        #pragma unroll 8
        for (int i = tid; i < F4_PER_BLOCK; i += 256)
            dst[i] = z;
    }

    // ---- router with 2-deep async staging pipeline ----
    float val[64];
    #pragma unroll
    for (int i = 0; i < 64; ++i) val[i] = 0.0f;

    float (*sbuf0)[256] = stage_lds[wave][0];
    float (*sbuf1)[256] = stage_lds[wave][1];

    stage_chunk(in, noise, sbuf0, g0, 0, lane);
    stage_chunk(in, noise, sbuf1, g0, 1, lane);

    asm volatile("s_waitcnt vmcnt(8)" ::: "memory");   // chunk 0 landed
    compute_chunk(w, sbuf0, val, 0, lane);
    asm volatile("s_waitcnt lgkmcnt(0)" ::: "memory"); // ds_reads of buf0 done
    stage_chunk(in, noise, sbuf0, g0, 2, lane);

    asm volatile("s_waitcnt vmcnt(8)" ::: "memory");   // chunk 1 landed
    compute_chunk(w, sbuf1, val, 1, lane);
    asm volatile("s_waitcnt lgkmcnt(0)" ::: "memory"); // ds_reads of buf1 done
    stage_chunk(in, noise, sbuf1, g0, 3, lane);

    asm volatile("s_waitcnt vmcnt(8)" ::: "memory");   // chunk 2 landed
    compute_chunk(w, sbuf0, val, 2, lane);

    asm volatile("s_waitcnt vmcnt(0)" ::: "memory");   // chunk 3 landed
    compute_chunk(w, sbuf1, val, 3, lane);

    // Butterfly transpose-reduce: 63 shuffles; lane l ends with the full dot
    // for flattened idx l (bitrev6 flatten compensates the halving order).
    #pragma unroll
    for (int m = 0; m < 6; ++m) {
        const int half = 32 >> m;
        const int bit  = (lane >> m) & 1;
        #pragma unroll
        for (int j = 0; j < half; ++j) {
            const float send = bit ? val[j] : val[j + half];
            const float recv = __shfl_xor(send, 1 << m, 64);
            val[j] = (bit ? val[j + half] : val[j]) + recv;
        }
    }

    const int tk = lane >> 4;
    const int e  = lane & 15;
    const float logit = val[0];
    const int g = g0 + tk;

    // 16-lane-group max with first-index tie-break
    float mv = logit; int am = e;
    #pragma unroll
    for (int msk = 1; msk <= 8; msk <<= 1) {
        const float ov = __shfl_xor(mv, msk, 64);
        const int   oe = __shfl_xor(am, msk, 64);
        if (ov > mv || (ov == mv && oe < am)) { mv = ov; am = oe; }
    }

    const float p = __expf(logit - mv);
    float s = p;
    #pragma unroll
    for (int msk = 1; msk <= 8; msk <<= 1)
        s += __shfl_xor(s, msk, 64);

    const float inv = 1.0f / s;
    if (e == am) {                       // exactly one lane per token
        gate[g]  = inv;                  // probs[argmax] = exp(0)/s
        index[g] = am;
        atomicAdd(&hcnt[am], 1);
    }

    // per-e total of normalized probs over this wave's 4 tokens: after
    // xor-16/32 all lanes hold the wave total; lanes 0..15 add once.
    float pn = p * inv;
    pn += __shfl_xor(pn, 16, 64);
    pn += __shfl_xor(pn, 32, 64);
    if (lane < 16)
        atomicAdd(&psum[e], pn);

    __syncthreads();
    if (tid < 16) {
        const int c = blockIdx.x >> 8;   // 256 blocks per c
        atomicAdd(&auxpart[c * 16 + tid], psum[tid]);
        atomicAdd(&counts [c * 16 + tid], hcnt[tid]);
    }

    // ---- even blocks: fill after routing ----
    if (!(blockIdx.x & 1)) {
        #pragma unroll 8
        for (int i = tid; i < F4_PER_BLOCK; i += 256)
            dst[i] = z;
    }
}

// ---------------------------------------------------------------------------
// Finalize: <=64 nonzeros (torch scatter semantics: only tokens tp<16, e=0
// slice). Rank within expert 0 computed from the first 16 indices (<=16<CAP).
// ---------------------------------------------------------------------------
__global__ __launch_bounds__(64) void finalize_kernel(
    const float* __restrict__ gate, const int* __restrict__ index,
    const int* __restrict__ counts, const float* __restrict__ auxpart,
    float* __restrict__ out)
{
    const int id = threadIdx.x;          // 0..63
    const int c  = id >> 4;
    const int tp = id & 15;
    const int cnt = counts[id];

    float term = ((float)cnt * (1.0f / T_DIM)) * (auxpart[id] * (1.0f / T_DIM));

    if (cnt > 0) {                        // expert value tp appears as an argmax
        const int g     = c * T_DIM + tp;
        const int myidx = index[g];
        int s = 0;
        if (myidx == 0) {                 // 1-based rank within expert 0 among tokens 0..tp
            int r = 0;
            for (int t = 0; t <= tp; ++t)
                r += (index[c * T_DIM + t] == 0);
            s = r;
        }
        const size_t off = ((size_t)g * E_DIM + 0) * CAP + (size_t)s;
        out[off]            = 1.0f;       // dispatch
        out[OUT_ONE + off]  = gate[g];    // combine
    }

    #pragma unroll
    for (int off = 32; off; off >>= 1)
        term += __shfl_down(term, off, 64);
    if (id == 0)
        out[2 * OUT_ONE] = 16.0f * term;  // aux_loss = E * sum(density1*proxy)
}

extern "C" void kernel_launch(void* const* d_in, const int* in_sizes, int n_in,
                              void* d_out, int out_size, void* d_ws, size_t ws_size,
                              hipStream_t stream) {
    const float* in    = (const float*)d_in[0];
    const float* w     = (const float*)d_in[1];
    const float* noise = (const float*)d_in[2];
    float* out = (float*)d_out;

    char* ws = (char*)d_ws;
    float* auxpart = (float*)(ws);
    int*   counts  = (int*)(ws + 256);
    float* gate    = (float*)(ws + 512);
    int*   index   = (int*)(ws + 512 + 65536);

    (void)hipMemsetAsync(ws, 0, 512, stream);

    fused_router_fill_kernel<<<dim3(NBLOCKS), dim3(256), 0, stream>>>(
        in, w, noise, gate, index, auxpart, counts, (float4*)out);
    finalize_kernel<<<dim3(1), dim3(64), 0, stream>>>(gate, index, counts, auxpart, out);
}

// Round 15
// 193.382 us; speedup vs baseline: 2.2843x; 2.2843x over previous
//
#include <hip/hip_runtime.h>
#include <math.h>

#define C_DIM 4
#define T_DIM 4096
#define D_DIM 1024
#define E_DIM 16
#define CAP   320
#define CT    (C_DIM * T_DIM)               // 16384 tokens
#define OUT_ONE ((size_t)CT * E_DIM * CAP)  // 83,886,080 elements per big output

#define NBLOCKS 2048                         // 8 tokens per block (2 per wave)
#define N4      ((2 * OUT_ONE) / 4)          // 41,943,040 float4 to zero
#define F4_PER_BLOCK (N4 / NBLOCKS)          // 20480 float4 per block (320KB)

// compile-time 5-bit bit-reverse (flatten permutation for the butterfly reduce)
__host__ __device__ constexpr int bitrev5(int i) {
    return ((i & 1) << 4) | ((i & 2) << 2) | (i & 4) | ((i & 8) >> 2) | ((i & 16) >> 4);
}

// ws layout (bytes):
//   0      : auxpart f32[64]   (per-(c,e) softmax prob sums) - zeroed each call
//   256    : counts  i32[64]   (per-(c,e) argmax histogram)  - zeroed each call
//   512    : gate    f32[CT]
//   66048  : index   i32[CT]

// async global->LDS, 16B per lane: LDS dest = uniform base + lane*16,
// global src = per-lane address. Proven correct in R14 (absmax 0).
__device__ __forceinline__ void gl_lds16(const float* g, float* l) {
    __builtin_amdgcn_global_load_lds(
        (const __attribute__((address_space(1))) void*)g,
        (__attribute__((address_space(3))) void*)l,
        16, 0, 0);
}

// stage one 256-float chunk (r) of 2 tokens' in+noise: 4 fire-and-forget ops.
__device__ __forceinline__ void stage_chunk(
    const float* __restrict__ in, const float* __restrict__ noise,
    float (*buf)[256], int g0, int r, int lane)
{
    const size_t base = (size_t)g0 * D_DIM + r * 256 + lane * 4;
    gl_lds16(in    + base,                  &buf[0][0]);
    gl_lds16(in    + base + D_DIM,          &buf[1][0]);
    gl_lds16(noise + base,                  &buf[2][0]);
    gl_lds16(noise + base + D_DIM,          &buf[3][0]);
}

// consume one staged chunk: x from LDS, FMA against 16 W rows (L1/L2 float4).
__device__ __forceinline__ void compute_chunk(
    const float* __restrict__ w, float (*buf)[256], float* val, int r, int lane)
{
    const int d0 = r * 256 + lane * 4;
    float4 x[2];
    #pragma unroll
    for (int tk = 0; tk < 2; ++tk) {
        const float4 a = *(const float4*)&buf[tk][lane * 4];
        const float4 n = *(const float4*)&buf[2 + tk][lane * 4];
        x[tk] = make_float4(a.x * n.x, a.y * n.y, a.z * n.z, a.w * n.w);
    }
    #pragma unroll
    for (int e = 0; e < 16; ++e) {
        const float4 wv = *(const float4*)(w + e * D_DIM + d0);
        #pragma unroll
        for (int tk = 0; tk < 2; ++tk)
            val[bitrev5(tk * 16 + e)] += x[tk].x * wv.x + x[tk].y * wv.y
                                       + x[tk].z * wv.z + x[tk].w * wv.w;
    }
}

// ---------------------------------------------------------------------------
// 2 tokens/wave (val[32], ~75 VGPR: below the spill threshold that killed
// R9/R14's val[64] inline-asm builds) + global_load_lds async staging (no
// VGPR destinations -> 8KB in flight/wave, read phase at BW instead of
// latency-bound ~2TB/s) + counted vmcnt pipeline + R7/R8 stagger parity.
// ---------------------------------------------------------------------------
__global__ __launch_bounds__(256) void fused_router_fill_kernel(
    const float* __restrict__ in, const float* __restrict__ w,
    const float* __restrict__ noise, float* __restrict__ gate,
    int* __restrict__ index, float* __restrict__ auxpart,
    int* __restrict__ counts, float4* __restrict__ out4)
{
    __shared__ float stage_lds[4][2][4][256];   // wave, dbuf, {2 in,2 noise}, 32KB
    __shared__ float psum[E_DIM];
    __shared__ int   hcnt[E_DIM];
    const int tid = threadIdx.x;
    if (tid < E_DIM) { psum[tid] = 0.0f; hcnt[tid] = 0; }
    __syncthreads();

    const int wave = tid >> 6;
    const int lane = tid & 63;
    const int g0   = blockIdx.x * 8 + wave * 2;    // 2 tokens per wave

    const float4 z = make_float4(0.f, 0.f, 0.f, 0.f);
    float4* dst = out4 + (size_t)blockIdx.x * F4_PER_BLOCK;

    // ---- odd blocks: fill first (stagger parity) ----
    if (blockIdx.x & 1) {
        #pragma unroll 8
        for (int i = tid; i < F4_PER_BLOCK; i += 256)
            dst[i] = z;
    }

    // ---- router with 2-deep async staging pipeline ----
    float val[32];
    #pragma unroll
    for (int i = 0; i < 32; ++i) val[i] = 0.0f;

    float (*sbuf0)[256] = stage_lds[wave][0];
    float (*sbuf1)[256] = stage_lds[wave][1];

    stage_chunk(in, noise, sbuf0, g0, 0, lane);
    stage_chunk(in, noise, sbuf1, g0, 1, lane);

    asm volatile("s_waitcnt vmcnt(4)" ::: "memory");   // chunk 0 landed
    compute_chunk(w, sbuf0, val, 0, lane);
    asm volatile("s_waitcnt lgkmcnt(0)" ::: "memory"); // buf0 ds_reads done
    stage_chunk(in, noise, sbuf0, g0, 2, lane);

    asm volatile("s_waitcnt vmcnt(4)" ::: "memory");   // chunk 1 landed
    compute_chunk(w, sbuf1, val, 1, lane);
    asm volatile("s_waitcnt lgkmcnt(0)" ::: "memory"); // buf1 ds_reads done
    stage_chunk(in, noise, sbuf1, g0, 3, lane);

    asm volatile("s_waitcnt vmcnt(4)" ::: "memory");   // chunk 2 landed
    compute_chunk(w, sbuf0, val, 2, lane);

    asm volatile("s_waitcnt vmcnt(0)" ::: "memory");   // chunk 3 landed
    compute_chunk(w, sbuf1, val, 3, lane);

    // butterfly transpose-reduce within 32-lane groups (R12-verified):
    // 5 levels, 31 shuffles; bitrev5 flatten compensates the halving order.
    #pragma unroll
    for (int m = 0; m < 5; ++m) {
        const int half = 16 >> m;
        const int bit  = (lane >> m) & 1;
        #pragma unroll
        for (int j = 0; j < half; ++j) {
            const float send = bit ? val[j] : val[j + half];
            const float recv = __shfl_xor(send, 1 << m, 64);
            val[j] = (bit ? val[j + half] : val[j]) + recv;
        }
    }
    float logit = val[0];
    logit += __shfl_xor(logit, 32, 64);
    // lane l holds the complete logit for (tk=(l>>4)&1, e=l&15)

    const int tk = (lane >> 4) & 1;
    const int e  = lane & 15;
    const int g  = g0 + tk;

    // 16-lane-group max with first-index tie-break
    float mv = logit; int am = e;
    #pragma unroll
    for (int msk = 1; msk <= 8; msk <<= 1) {
        const float ov = __shfl_xor(mv, msk, 64);
        const int   oe = __shfl_xor(am, msk, 64);
        if (ov > mv || (ov == mv && oe < am)) { mv = ov; am = oe; }
    }

    const float p = __expf(logit - mv);
    float s = p;
    #pragma unroll
    for (int msk = 1; msk <= 8; msk <<= 1)
        s += __shfl_xor(s, msk, 64);

    const float inv = 1.0f / s;
    if (lane < 32 && e == am) {          // exactly one lane per token
        gate[g]  = inv;                  // probs[argmax] = exp(0)/s
        index[g] = am;
        atomicAdd(&hcnt[am], 1);
    }

    // per-e total over this wave's 2 tokens; lanes 0..15 add once.
    float pn = p * inv;
    pn += __shfl_xor(pn, 16, 64);
    if (lane < 16)
        atomicAdd(&psum[e], pn);

    __syncthreads();
    if (tid < 16) {
        const int c = blockIdx.x >> 9;   // 512 blocks per c
        atomicAdd(&auxpart[c * 16 + tid], psum[tid]);
        atomicAdd(&counts [c * 16 + tid], hcnt[tid]);
    }

    // ---- even blocks: fill after routing ----
    if (!(blockIdx.x & 1)) {
        #pragma unroll 8
        for (int i = tid; i < F4_PER_BLOCK; i += 256)
            dst[i] = z;
    }
}

// ---------------------------------------------------------------------------
// Finalize: <=64 nonzeros (torch scatter semantics: only tokens tp<16, e=0
// slice). Rank within expert 0 computed from the first 16 indices (<=16<CAP).
// ---------------------------------------------------------------------------
__global__ __launch_bounds__(64) void finalize_kernel(
    const float* __restrict__ gate, const int* __restrict__ index,
    const int* __restrict__ counts, const float* __restrict__ auxpart,
    float* __restrict__ out)
{
    const int id = threadIdx.x;          // 0..63
    const int c  = id >> 4;
    const int tp = id & 15;
    const int cnt = counts[id];

    float term = ((float)cnt * (1.0f / T_DIM)) * (auxpart[id] * (1.0f / T_DIM));

    if (cnt > 0) {                        // expert value tp appears as an argmax
        const int g     = c * T_DIM + tp;
        const int myidx = index[g];
        int s = 0;
        if (myidx == 0) {                 // 1-based rank within expert 0 among tokens 0..tp
            int r = 0;
            for (int t = 0; t <= tp; ++t)
                r += (index[c * T_DIM + t] == 0);
            s = r;
        }
        const size_t off = ((size_t)g * E_DIM + 0) * CAP + (size_t)s;
        out[off]            = 1.0f;       // dispatch
        out[OUT_ONE + off]  = gate[g];    // combine
    }

    #pragma unroll
    for (int off = 32; off; off >>= 1)
        term += __shfl_down(term, off, 64);
    if (id == 0)
        out[2 * OUT_ONE] = 16.0f * term;  // aux_loss = E * sum(density1*proxy)
}

extern "C" void kernel_launch(void* const* d_in, const int* in_sizes, int n_in,
                              void* d_out, int out_size, void* d_ws, size_t ws_size,
                              hipStream_t stream) {
    const float* in    = (const float*)d_in[0];
    const float* w     = (const float*)d_in[1];
    const float* noise = (const float*)d_in[2];
    float* out = (float*)d_out;

    char* ws = (char*)d_ws;
    float* auxpart = (float*)(ws);
    int*   counts  = (int*)(ws + 256);
    float* gate    = (float*)(ws + 512);
    int*   index   = (int*)(ws + 512 + 65536);

    (void)hipMemsetAsync(ws, 0, 512, stream);

    fused_router_fill_kernel<<<dim3(NBLOCKS), dim3(256), 0, stream>>>(
        in, w, noise, gate, index, auxpart, counts, (float4*)out);
    finalize_kernel<<<dim3(1), dim3(64), 0, stream>>>(gate, index, counts, auxpart, out);
}

// Round 16
// 186.307 us; speedup vs baseline: 2.3710x; 1.0380x over previous
//
#include <hip/hip_runtime.h>
#include <math.h>

#define C_DIM 4
#define T_DIM 4096
#define D_DIM 1024
#define E_DIM 16
#define CAP   320
#define CT    (C_DIM * T_DIM)               // 16384 tokens
#define OUT_ONE ((size_t)CT * E_DIM * CAP)  // 83,886,080 elements per big output

#define NBLOCKS 1024                         // 16 tokens per block (4 per router wave)
#define N4      ((2 * OUT_ONE) / 4)          // 41,943,040 float4 to zero
#define F4_PER_BLOCK (N4 / NBLOCKS)          // 40960 float4 per block (640KB)
#define F4_FILLWAVES 30720                   // waves 4-7 fill this prefix (120 iters)
#define F4_TAIL (F4_PER_BLOCK - F4_FILLWAVES)// router waves fill suffix (40 iters)

// compile-time 6-bit bit-reverse (flatten permutation for the butterfly reduce)
__host__ __device__ constexpr int bitrev6(int i) {
    return ((i & 1) << 5) | ((i & 2) << 3) | ((i & 4) << 1)
         | ((i & 8) >> 1) | ((i & 16) >> 3) | ((i & 32) >> 5);
}

// ws layout (bytes):
//   0      : auxpart f32[64]   (per-(c,e) softmax prob sums) - zeroed each call
//   256    : counts  i32[64]   (per-(c,e) argmax histogram)  - zeroed each call
//   512    : gate    f32[CT]
//   66048  : index   i32[CT]

// ---------------------------------------------------------------------------
// WAVE SPECIALIZATION: 512-thread blocks. Waves 0-3 run R8's router (4
// tokens/wave, plain VGPR loads, butterfly reduce, wave-parallel softmax);
// waves 4-7 stream-fill the block's output slice concurrently. Unlike the
// phase-stagger (R7/R8), read and write streams are continuously mixed for
// the whole dispatch — no pure-read or pure-write epochs, no store-drain
// coupling (R15's async failure mode). Router waves pick up the last 25% of
// the fill after their epilogue to balance wave time.
// ---------------------------------------------------------------------------
__global__ void fused_router_fill_kernel(
    const float* __restrict__ in, const float* __restrict__ w,
    const float* __restrict__ noise, float* __restrict__ gate,
    int* __restrict__ index, float* __restrict__ auxpart,
    int* __restrict__ counts, float4* __restrict__ out4)
{
    __shared__ float psum[E_DIM];
    __shared__ int   hcnt[E_DIM];
    const int tid = threadIdx.x;
    if (tid < E_DIM) { psum[tid] = 0.0f; hcnt[tid] = 0; }
    __syncthreads();

    const int wave = tid >> 6;
    const int lane = tid & 63;
    const float4 z = make_float4(0.f, 0.f, 0.f, 0.f);
    float4* dst = out4 + (size_t)blockIdx.x * F4_PER_BLOCK;

    if (wave >= 4) {
        // ---- fill waves: stream the 480KB prefix ----
        const int t = tid - 256;                 // 0..255
        #pragma unroll 8
        for (int j = 0; j < 120; ++j)
            dst[t + 256 * j] = z;
    } else {
        // ---- router waves: R8's proven body ----
        const int g0 = blockIdx.x * 16 + wave * 4;   // 4 tokens per wave

        float val[64];
        #pragma unroll
        for (int i = 0; i < 64; ++i) val[i] = 0.0f;

        #pragma unroll
        for (int r = 0; r < 4; ++r) {
            const int d0 = r * 256 + lane * 4;
            float4 x[4];
            #pragma unroll
            for (int tk = 0; tk < 4; ++tk) {
                const float4 a = *(const float4*)(in    + (size_t)(g0 + tk) * D_DIM + d0);
                const float4 n = *(const float4*)(noise + (size_t)(g0 + tk) * D_DIM + d0);
                x[tk] = make_float4(a.x * n.x, a.y * n.y, a.z * n.z, a.w * n.w);
            }
            #pragma unroll
            for (int e = 0; e < 16; ++e) {
                const float4 wv = *(const float4*)(w + e * D_DIM + d0);
                #pragma unroll
                for (int tk = 0; tk < 4; ++tk) {
                    val[bitrev6(tk * 16 + e)] += x[tk].x * wv.x + x[tk].y * wv.y
                                               + x[tk].z * wv.z + x[tk].w * wv.w;
                }
            }
        }

        // Butterfly transpose-reduce: 63 shuffles; lane l ends with the full
        // dot for flattened idx l (bitrev6 compensates the halving order).
        #pragma unroll
        for (int m = 0; m < 6; ++m) {
            const int half = 32 >> m;
            const int bit  = (lane >> m) & 1;
            #pragma unroll
            for (int j = 0; j < half; ++j) {
                const float send = bit ? val[j] : val[j + half];
                const float recv = __shfl_xor(send, 1 << m, 64);
                val[j] = (bit ? val[j + half] : val[j]) + recv;
            }
        }

        const int tk = lane >> 4;
        const int e  = lane & 15;
        const float logit = val[0];
        const int g = g0 + tk;

        // 16-lane-group max with first-index tie-break
        float mv = logit; int am = e;
        #pragma unroll
        for (int msk = 1; msk <= 8; msk <<= 1) {
            const float ov = __shfl_xor(mv, msk, 64);
            const int   oe = __shfl_xor(am, msk, 64);
            if (ov > mv || (ov == mv && oe < am)) { mv = ov; am = oe; }
        }

        const float p = __expf(logit - mv);
        float s = p;
        #pragma unroll
        for (int msk = 1; msk <= 8; msk <<= 1)
            s += __shfl_xor(s, msk, 64);

        const float inv = 1.0f / s;
        if (e == am) {                       // exactly one lane per token
            gate[g]  = inv;                  // probs[argmax] = exp(0)/s
            index[g] = am;
            atomicAdd(&hcnt[am], 1);
        }

        // per-e total of normalized probs over this wave's 4 tokens: after
        // xor-16/32 all lanes hold the wave total; lanes 0..15 add once.
        float pn = p * inv;
        pn += __shfl_xor(pn, 16, 64);
        pn += __shfl_xor(pn, 32, 64);
        if (lane < 16)
            atomicAdd(&psum[e], pn);

        // ---- router waves' fill tail: the 160KB suffix ----
        #pragma unroll 8
        for (int j = 0; j < 40; ++j)
            dst[F4_FILLWAVES + tid + 256 * j] = z;
    }

    __syncthreads();
    if (tid < 16) {
        const int c = blockIdx.x >> 8;   // 256 blocks per c
        atomicAdd(&auxpart[c * 16 + tid], psum[tid]);
        atomicAdd(&counts [c * 16 + tid], hcnt[tid]);
    }
}

// ---------------------------------------------------------------------------
// Finalize: <=64 nonzeros (torch scatter semantics: only tokens tp<16, e=0
// slice). Rank within expert 0 computed from the first 16 indices (<=16<CAP).
// ---------------------------------------------------------------------------
__global__ __launch_bounds__(64) void finalize_kernel(
    const float* __restrict__ gate, const int* __restrict__ index,
    const int* __restrict__ counts, const float* __restrict__ auxpart,
    float* __restrict__ out)
{
    const int id = threadIdx.x;          // 0..63
    const int c  = id >> 4;
    const int tp = id & 15;
    const int cnt = counts[id];

    float term = ((float)cnt * (1.0f / T_DIM)) * (auxpart[id] * (1.0f / T_DIM));

    if (cnt > 0) {                        // expert value tp appears as an argmax
        const int g     = c * T_DIM + tp;
        const int myidx = index[g];
        int s = 0;
        if (myidx == 0) {                 // 1-based rank within expert 0 among tokens 0..tp
            int r = 0;
            for (int t = 0; t <= tp; ++t)
                r += (index[c * T_DIM + t] == 0);
            s = r;
        }
        const size_t off = ((size_t)g * E_DIM + 0) * CAP + (size_t)s;
        out[off]            = 1.0f;       // dispatch
        out[OUT_ONE + off]  = gate[g];    // combine
    }

    #pragma unroll
    for (int off = 32; off; off >>= 1)
        term += __shfl_down(term, off, 64);
    if (id == 0)
        out[2 * OUT_ONE] = 16.0f * term;  // aux_loss = E * sum(density1*proxy)
}

extern "C" void kernel_launch(void* const* d_in, const int* in_sizes, int n_in,
                              void* d_out, int out_size, void* d_ws, size_t ws_size,
                              hipStream_t stream) {
    const float* in    = (const float*)d_in[0];
    const float* w     = (const float*)d_in[1];
    const float* noise = (const float*)d_in[2];
    float* out = (float*)d_out;

    char* ws = (char*)d_ws;
    float* auxpart = (float*)(ws);
    int*   counts  = (int*)(ws + 256);
    float* gate    = (float*)(ws + 512);
    int*   index   = (int*)(ws + 512 + 65536);

    (void)hipMemsetAsync(ws, 0, 512, stream);

    fused_router_fill_kernel<<<dim3(NBLOCKS), dim3(512), 0, stream>>>(
        in, w, noise, gate, index, auxpart, counts, (float4*)out);
    finalize_kernel<<<dim3(1), dim3(64), 0, stream>>>(gate, index, counts, auxpart, out);
}